// Round 1
// baseline (453.289 us; speedup 1.0000x reference)
//
#include <hip/hip_runtime.h>

// SSIM, B=16, C=1, H=W=1024, 11x11 separable Gaussian (sigma=20 -> near-flat).
// Single fused tiled kernel: per 64x64 output tile
//   phase 1: horizontal blur of img (84 rows x 74 cols) from global -> LDS S
//   phase 2: vertical blur -> mu (74x74) in LDS M
//   phase 2.5: stash inner mu in registers (16 px/thread)
//   phase 2.75: M <- d = img - mu (0 outside image); fused global min/max
//   phase 3/4 (x3 stats): fused square+horizontal blur -> HP (in S), vertical
//            blur -> per-thread register stats s11,s22,s12
//   combine: 1st-order Taylor in (C1,C2) -> three C-independent sums.
// Finalize kernel applies C1,C2 from the min/max (val_range) and writes
// out = 1 - mean. Taylor error ~1e-8 vs threshold 1.5e-3.

#define IMG_H 1024
#define IMG_W 1024
#define TS    64          // output tile (square); 1024 % 64 == 0 -> no partial tiles
#define MW    74          // TS + 10 (mu/d region)
#define MST   76          // padded LDS stride (multiple of 4 -> float4-aligned rows)
#define HR    84          // TS + 20 (rows needed for horizontal pass)
#define HST   76          // Hbuf stride
#define HPW   64          // HP (product blur) width = TS
#define NSTRIP 19         // ceil(74/4) column strips in phase 1

__device__ __forceinline__ unsigned fkey(float f) {
  unsigned b = __float_as_uint(f);
  return (b & 0x80000000u) ? ~b : (b | 0x80000000u);   // order-preserving map
}
__device__ __forceinline__ float funkey(unsigned k) {
  return (k & 0x80000000u) ? __uint_as_float(k & 0x7FFFFFFFu)
                           : __uint_as_float(~k);
}

__global__ void ssim_init(unsigned* __restrict__ ws) {
  ws[0] = 0u;           // sum S0*B0   (float 0.0 bits)
  ws[1] = 0u;           // sum S0*B'   (C1 coefficient)
  ws[2] = 0u;           // sum B0*S'   (C2 coefficient)
  ws[3] = 0xFFFFFFFFu;  // min key
  ws[4] = 0u;           // max key
}

// one statistic: fused (product + horizontal blur) -> HP in S, then vertical
// blur into dst registers. SIDX: 0 = d1*d1, 1 = d2*d2, 2 = d1*d2.
template <int SIDX>
__device__ __forceinline__ void stat_pass(int tid, const float g[11],
                                          float* __restrict__ S,
                                          const float* __restrict__ M1,
                                          const float* __restrict__ M2,
                                          int R0o, int c_own, float dst[16]) {
  __syncthreads();  // S free to overwrite, M ready
  for (unsigned idx = tid; idx < MW * 16u; idx += 256) {
    unsigned i = idx >> 4;
    int oc0 = (int)(idx & 15u) * 4;
    float a[16], b[16];
    if (SIDX != 1) {
      const float4* p = (const float4*)&M1[i * MST + oc0];  // 16B-aligned
      #pragma unroll
      for (int k = 0; k < 4; ++k) {
        float4 t = p[k];
        a[4 * k] = t.x; a[4 * k + 1] = t.y; a[4 * k + 2] = t.z; a[4 * k + 3] = t.w;
      }
    }
    if (SIDX != 0) {
      const float4* p = (const float4*)&M2[i * MST + oc0];
      #pragma unroll
      for (int k = 0; k < 4; ++k) {
        float4 t = p[k];
        b[4 * k] = t.x; b[4 * k + 1] = t.y; b[4 * k + 2] = t.z; b[4 * k + 3] = t.w;
      }
    }
    float w[14];
    #pragma unroll
    for (int k = 0; k < 14; ++k)
      w[k] = (SIDX == 0) ? a[k] * a[k] : (SIDX == 1) ? b[k] * b[k] : a[k] * b[k];
    float4 o;
    {
      float oq[4];
      #pragma unroll
      for (int q = 0; q < 4; ++q) {
        float acc = 0.f;
        #pragma unroll
        for (int j = 0; j < 11; ++j) acc = fmaf(g[j], w[q + j], acc);
        oq[q] = acc;
      }
      o.x = oq[0]; o.y = oq[1]; o.z = oq[2]; o.w = oq[3];
    }
    *(float4*)&S[i * HPW + oc0] = o;  // HP layout: MW x 64, 16B-aligned
  }
  __syncthreads();
  // vertical blur: thread owns col c_own, rows [R0o, R0o+16)
  float win[26];
  #pragma unroll
  for (int j = 0; j < 26; ++j) win[j] = S[(R0o + j) * HPW + c_own];
  #pragma unroll
  for (int k = 0; k < 16; ++k) {
    float acc = 0.f;
    #pragma unroll
    for (int j = 0; j < 11; ++j) acc = fmaf(g[j], win[k + j], acc);
    dst[k] = acc;
  }
}

__global__ __launch_bounds__(256, 2)
void ssim_main(const float* __restrict__ img1, const float* __restrict__ img2,
               const float* __restrict__ kern, unsigned* __restrict__ ws) {
  __shared__ __align__(16) float S[HR * HST];    // 84*76: H-blur buf, reused as HP
  __shared__ __align__(16) float M1[MW * MST];   // mu1 then d1
  __shared__ __align__(16) float M2[MW * MST];   // mu2 then d2
  __shared__ float gsh[16];
  __shared__ float redbuf[4][8];

  const int tid = threadIdx.x;
  const int r0 = blockIdx.y * TS;
  const int c0 = blockIdx.x * TS;
  const size_t boff = (size_t)blockIdx.z * (IMG_H * IMG_W);
  const float* i1 = img1 + boff;
  const float* i2 = img2 + boff;

  // separable weights from the 2D kernel: g[j] = k2d[5][j] / sqrt(k2d[5][5])
  if (tid < 11) gsh[tid] = kern[55 + tid] * rsqrtf(kern[60]);
  __syncthreads();
  float g[11];
  #pragma unroll
  for (int j = 0; j < 11; ++j) g[j] = gsh[j];

  // ---- mu for both images ----
  #pragma unroll
  for (int im = 0; im < 2; ++im) {
    const float* img = im ? i2 : i1;
    float* M = im ? M2 : M1;
    if (im) __syncthreads();  // S reuse
    // phase 1: horizontal blur into S. Valid cols cc<74; pad cols hold garbage
    // (never read). Zero-padding outside the image.
    for (unsigned idx = tid; idx < HR * NSTRIP; idx += 256) {
      unsigned rr = idx / NSTRIP;
      unsigned strip = idx - rr * NSTRIP;
      int cc0 = (int)strip * 4;
      int gr = r0 - 10 + (int)rr;
      int gcb = c0 + cc0 - 10;   // global col of w[0]
      float w[14];
      if (gr >= 0 && gr < IMG_H) {
        const float* rowp = img + (size_t)gr * IMG_W;
        if (gcb >= 0 && gcb + 14 <= IMG_W) {
          const float2* p2 = (const float2*)(rowp + gcb);  // gcb even -> 8B aligned
          #pragma unroll
          for (int k = 0; k < 7; ++k) {
            float2 t = p2[k];
            w[2 * k] = t.x; w[2 * k + 1] = t.y;
          }
        } else {
          #pragma unroll
          for (int k = 0; k < 14; ++k) {
            int gc = gcb + k;
            w[k] = (gc >= 0 && gc < IMG_W) ? rowp[gc] : 0.f;
          }
        }
      } else {
        #pragma unroll
        for (int k = 0; k < 14; ++k) w[k] = 0.f;
      }
      #pragma unroll
      for (int q = 0; q < 4; ++q) {
        float acc = 0.f;
        #pragma unroll
        for (int j = 0; j < 11; ++j) acc = fmaf(g[j], w[q + j], acc);
        S[rr * HST + cc0 + q] = acc;
      }
    }
    __syncthreads();
    // phase 2: vertical blur S -> M (mu), 74x74 valid; 8-row sliding windows
    for (unsigned idx = tid; idx < 10u * MW; idx += 256) {
      unsigned rbv = idx / MW;
      unsigned cc = idx - rbv * MW;
      int R0v = (int)rbv * 8;
      float win[18];
      #pragma unroll
      for (int j = 0; j < 18; ++j) {
        int rr = R0v + j;
        win[j] = (rr < HR) ? S[rr * HST + cc] : 0.f;
      }
      #pragma unroll
      for (int q = 0; q < 8; ++q) {
        int r2 = R0v + q;
        if (r2 < MW) {
          float acc = 0.f;
          #pragma unroll
          for (int j = 0; j < 11; ++j) acc = fmaf(g[j], win[q + j], acc);
          M[r2 * MST + cc] = acc;
        }
      }
    }
    __syncthreads();
  }

  // phase 2.5: stash inner mu (output pixels) in registers.
  // thread owns col c_own, rows [R0o, R0o+16) of the 64x64 tile.
  const int c_own = tid & 63;
  const int rb_own = tid >> 6;
  const int R0o = rb_own * 16;
  float mu1r[16], mu2r[16];
  #pragma unroll
  for (int k = 0; k < 16; ++k) {
    mu1r[k] = M1[(R0o + k + 5) * MST + c_own + 5];
    mu2r[k] = M2[(R0o + k + 5) * MST + c_own + 5];
  }
  __syncthreads();

  // phase 2.75: M <- d = img - mu (0 outside the image, matching the
  // zero-padded second conv); fused global min/max over in-bounds pixels.
  float vmin = 1e30f, vmax = -1e30f;
  for (unsigned idx = tid; idx < MW * MW; idx += 256) {
    unsigned i = idx / MW;
    unsigned j = idx - i * MW;
    int gr = r0 - 5 + (int)i;
    int gc = c0 - 5 + (int)j;
    float d1 = 0.f, d2 = 0.f;
    if (gr >= 0 && gr < IMG_H && gc >= 0 && gc < IMG_W) {
      size_t off = (size_t)gr * IMG_W + gc;
      float v1 = i1[off], v2 = i2[off];
      vmin = fminf(vmin, fminf(v1, v2));
      vmax = fmaxf(vmax, fmaxf(v1, v2));
      d1 = v1 - M1[i * MST + j];
      d2 = v2 - M2[i * MST + j];
    }
    M1[i * MST + j] = d1;
    M2[i * MST + j] = d2;
  }

  // phases 3/4 for the three statistics
  float s11r[16], s22r[16], s12r[16];
  stat_pass<0>(tid, g, S, M1, M2, R0o, c_own, s11r);
  stat_pass<1>(tid, g, S, M1, M2, R0o, c_own, s22r);
  stat_pass<2>(tid, g, S, M1, M2, R0o, c_own, s12r);

  // combine: ssim ~= S0*B0 + C1*(S0*B') + C2*(B0*S')  (1st-order Taylor)
  float acc0 = 0.f, aC1 = 0.f, aC2 = 0.f;
  #pragma unroll
  for (int k = 0; k < 16; ++k) {
    float s1 = s11r[k] + 1.f;           // sigma1_sq
    float s2 = s22r[k] + 1.f;           // sigma2_sq
    float s12v = s12r[k] + 1.f;         // sigma12
    float m1 = mu1r[k], m2 = mu2r[k];
    float a = 2.f * s12v;               // structure numerator @ C2=0
    float b = s1 + s2;                  // structure denominator @ C2=0 (>= 2)
    float rb = __builtin_amdgcn_rcpf(b);
    float S0 = a * rb;
    float Sp = (b - a) * rb * rb;       // dS/dC2
    float m12 = fmaf(m1, m2, 1.f);      // mu1mu2
    float nb = 2.f * m12;
    float N1 = nb * nb;                 // (2*mu1mu2)^2
    float ms = fmaf(m1, m1, fmaf(m2, m2, 2.f));  // mu1_sq + mu2_sq
    float D1 = ms * ms;
    float rD = __builtin_amdgcn_rcpf(D1);
    float B0 = N1 * rD;
    float Bp = (D1 - N1) * rD * rD;     // dB/dC1
    acc0 = fmaf(S0, B0, acc0);
    aC1 = fmaf(S0, Bp, aC1);
    aC2 = fmaf(B0, Sp, aC2);
  }

  // block reduction: wave shuffle (64 lanes) then 4 wave partials via LDS
  #pragma unroll
  for (int off = 32; off > 0; off >>= 1) {
    acc0 += __shfl_down(acc0, off);
    aC1 += __shfl_down(aC1, off);
    aC2 += __shfl_down(aC2, off);
    vmin = fminf(vmin, __shfl_down(vmin, off));
    vmax = fmaxf(vmax, __shfl_down(vmax, off));
  }
  const int wv = tid >> 6, ln = tid & 63;
  if (ln == 0) {
    redbuf[wv][0] = acc0; redbuf[wv][1] = aC1; redbuf[wv][2] = aC2;
    redbuf[wv][3] = vmin; redbuf[wv][4] = vmax;
  }
  __syncthreads();
  if (tid == 0) {
    float t0 = 0.f, t1 = 0.f, t2 = 0.f, mn = 1e30f, mx = -1e30f;
    #pragma unroll
    for (int w2 = 0; w2 < 4; ++w2) {
      t0 += redbuf[w2][0]; t1 += redbuf[w2][1]; t2 += redbuf[w2][2];
      mn = fminf(mn, redbuf[w2][3]); mx = fmaxf(mx, redbuf[w2][4]);
    }
    float* wsF = (float*)ws;
    atomicAdd(&wsF[0], t0);
    atomicAdd(&wsF[1], t1);
    atomicAdd(&wsF[2], t2);
    atomicMin(&ws[3], fkey(mn));
    atomicMax(&ws[4], fkey(mx));
  }
}

__global__ void ssim_final(const unsigned* __restrict__ ws, float* __restrict__ out) {
  const float* wsF = (const float*)ws;
  float mn = funkey(ws[3]);
  float mx = funkey(ws[4]);
  float vr = mx - mn + 1e-5f;
  float c1 = 0.01f * vr; c1 *= c1;
  float c2 = 0.03f * vr; c2 *= c2;
  float mean = (wsF[0] + c1 * wsF[1] + c2 * wsF[2]) * (1.0f / 16777216.0f);
  out[0] = 1.f - mean;
}

extern "C" void kernel_launch(void* const* d_in, const int* in_sizes, int n_in,
                              void* d_out, int out_size, void* d_ws, size_t ws_size,
                              hipStream_t stream) {
  const float* img1 = (const float*)d_in[0];
  const float* img2 = (const float*)d_in[1];
  const float* kern = (const float*)d_in[2];
  unsigned* ws = (unsigned*)d_ws;
  float* out = (float*)d_out;
  (void)in_sizes; (void)n_in; (void)out_size; (void)ws_size;

  hipLaunchKernelGGL(ssim_init, dim3(1), dim3(1), 0, stream, ws);
  hipLaunchKernelGGL(ssim_main, dim3(IMG_W / TS, IMG_H / TS, 16), dim3(256), 0,
                     stream, img1, img2, kern, ws);
  hipLaunchKernelGGL(ssim_final, dim3(1), dim3(1), 0, stream, ws, out);
}